// Round 1
// baseline (5096.917 us; speedup 1.0000x reference)
//
#include <hip/hip_runtime.h>

#define NN      8000
#define NEXC    6400
#define TSTEPS  200
#define TREF    20
#define NBLK    16
#define TPB     512
#define NTHREADS (NBLK * TPB)      // 8192
#define NWAVES   (NTHREADS / 64)   // 128

// ---------------- grid barrier (sense via generation counter) ----------------
__device__ __forceinline__ void grid_sync(unsigned* bar_cnt, unsigned* bar_gen) {
    __syncthreads();
    if (threadIdx.x == 0) {
        __threadfence();  // release: agent-scope L2 writeback of prior stores
        unsigned g = __hip_atomic_load(bar_gen, __ATOMIC_RELAXED, __HIP_MEMORY_SCOPE_AGENT);
        unsigned old = __hip_atomic_fetch_add(bar_cnt, 1u, __ATOMIC_RELAXED, __HIP_MEMORY_SCOPE_AGENT);
        if (old == (unsigned)(NBLK - 1)) {
            __hip_atomic_store(bar_cnt, 0u, __ATOMIC_RELAXED, __HIP_MEMORY_SCOPE_AGENT);
            __hip_atomic_store(bar_gen, g + 1u, __ATOMIC_RELEASE, __HIP_MEMORY_SCOPE_AGENT);
        } else {
            while (__hip_atomic_load(bar_gen, __ATOMIC_ACQUIRE, __HIP_MEMORY_SCOPE_AGENT) == g) {
                __builtin_amdgcn_s_sleep(1);
            }
        }
        __threadfence();  // acquire side: invalidate local caches
    }
    __syncthreads();
}

// -------- row_ptr from sorted pre_idx: row_ptr[i] = lower_bound(pre, i) ------
__global__ void build_rowptr(const int* __restrict__ pre, int nE, int* __restrict__ row_ptr) {
    int i = blockIdx.x * blockDim.x + threadIdx.x;
    if (i > NN) return;
    int lo = 0, hi = nE;
    while (lo < hi) {
        int mid = (lo + hi) >> 1;
        if (pre[mid] < i) lo = mid + 1; else hi = mid;
    }
    row_ptr[i] = lo;
}

__global__ void init_ws(unsigned* cnt, unsigned* scount, unsigned* bar) {
    int i = blockIdx.x * blockDim.x + threadIdx.x;
    if (i < NN) cnt[i] = 0u;
    if (i < 2) { scount[i] = 0u; bar[i] = 0u; }
}

// ------------------------------- simulation ----------------------------------
__global__ __launch_bounds__(TPB) void sim(
    const float* __restrict__ bg, const float* __restrict__ tau_m,
    const int* __restrict__ post_idx, const int* __restrict__ row_ptr,
    unsigned* __restrict__ cnt, int* __restrict__ slist,
    unsigned* __restrict__ scount, unsigned* __restrict__ bar,
    float* __restrict__ out)
{
#pragma clang fp contract(off)
    const int tid = blockIdx.x * TPB + threadIdx.x;
    const int i = tid;
    const bool own = (i < NN);

    const float JE = (float)(2.0 * (16.0 / 640.0));        // float32(0.05)
    const float JI = (float)(2.0 * (16.0 / 640.0) * 5.0);  // float32(0.25)
    const float DS = (float)0.98019867330675525;           // exp(-0.1/5)
    const float DA = (float)0.99950012497917929;           // exp(-0.1/200)

    float dv = 0.f, v = 0.f, s = 0.f, a = 0.f, spike = 0.f, sum_v = 0.f;
    int ref = 0, sum_spk = 0;
    if (own) dv = expf(-(0.1f / tau_m[i]));

    for (int t = 0; t < TSTEPS; ++t) {
        const int p = t & 1;

        // ---------------- Phase A: neuron update + spike list ----------------
        if (own) {
            unsigned c = __hip_atomic_load(&cnt[i], __ATOMIC_RELAXED, __HIP_MEMORY_SCOPE_AGENT);
            __hip_atomic_store(&cnt[i], 0u, __ATOMIC_RELAXED, __HIP_MEMORY_SCOPE_AGENT);
            float rec = (float)(c & 0xFFFFu) * JE - (float)(c >> 16) * JI;
            float bgt = bg[t * NN + i];
            s = s * DS + rec + bgt;
            a = a * DA + spike;
            bool active = (ref <= 0);
            v = active ? (v * dv + s) : 0.f;
            float thr = 20.0f + 1.6f * a;
            bool ns = (v >= thr) && active;
            if (ns) v = 0.f;
            ref = ns ? TREF : (ref > 0 ? ref - 1 : 0);
            spike = ns ? 1.f : 0.f;
            sum_spk += ns ? 1 : 0;
            sum_v += v;
            if (ns) {
                unsigned pos = atomicAdd(&scount[p], 1u);
                slist[p * NN + (int)pos] = i;
            }
        }
        if (tid == 0) {  // reset the other parity's counter (consumed last step)
            __hip_atomic_store(&scount[p ^ 1], 0u, __ATOMIC_RELAXED, __HIP_MEMORY_SCOPE_AGENT);
        }

        grid_sync(&bar[0], &bar[1]);

        // ------------- Phase B: cooperative scatter of spikes ----------------
        unsigned k = __hip_atomic_load(&scount[p], __ATOMIC_RELAXED, __HIP_MEMORY_SCOPE_AGENT);
        int wid = tid >> 6, lane = tid & 63;
        for (unsigned idx = (unsigned)wid; idx < k; idx += NWAVES) {
            int ps = slist[p * NN + (int)idx];
            int e0 = row_ptr[ps], e1 = row_ptr[ps + 1];
            unsigned addv = (ps < NEXC) ? 1u : 0x10000u;  // exc lo16 / inh hi16
            for (int e = e0 + lane; e < e1; e += 64) {
                atomicAdd(&cnt[post_idx[e]], addv);
            }
        }

        grid_sync(&bar[0], &bar[1]);
    }

    if (own) {
        out[i]      = (float)sum_spk / 200.0f;
        out[NN + i] = sum_v / 200.0f;
    }
}

// ------------------------------- launcher ------------------------------------
extern "C" void kernel_launch(void* const* d_in, const int* in_sizes, int n_in,
                              void* d_out, int out_size, void* d_ws, size_t ws_size,
                              hipStream_t stream) {
    const float* bg       = (const float*)d_in[1];
    const float* tau_m    = (const float*)d_in[2];
    const int*   pre_idx  = (const int*)d_in[3];
    const int*   post_idx = (const int*)d_in[4];
    const int    nE       = in_sizes[0];
    float* out = (float*)d_out;

    char* ws = (char*)d_ws;
    unsigned* cnt    = (unsigned*)(ws);                    // 8000
    int*      slist  = (int*)     (ws + (size_t)8000 * 4); // 2 * 8000
    unsigned* scount = (unsigned*)(ws + (size_t)24000 * 4);// 2
    unsigned* bar    = (unsigned*)(ws + (size_t)24002 * 4);// 2
    int*      row_ptr= (int*)     (ws + (size_t)24004 * 4);// 8001

    hipLaunchKernelGGL(build_rowptr, dim3(32), dim3(256), 0, stream, pre_idx, nE, row_ptr);
    hipLaunchKernelGGL(init_ws, dim3(32), dim3(256), 0, stream, cnt, scount, bar);
    hipLaunchKernelGGL(sim, dim3(NBLK), dim3(TPB), 0, stream,
                       bg, tau_m, post_idx, row_ptr, cnt, slist, scount, bar, out);
}

// Round 2
// 3080.413 us; speedup vs baseline: 1.6546x; 1.6546x over previous
//
#include <hip/hip_runtime.h>

#define NN      8000
#define NEXC    6400
#define TSTEPS  200
#define TREF    20
#define NBLK    64
#define TPB     1024
#define NPB     125            // neurons per block: 64 * 125 = 8000

// ---------------- grid barrier (sense via generation counter) ----------------
__device__ __forceinline__ void grid_sync(unsigned* bar_cnt, unsigned* bar_gen) {
    __syncthreads();
    if (threadIdx.x == 0) {
        __threadfence();  // release: prior stores (L1 is write-through; flush L2)
        unsigned g = __hip_atomic_load(bar_gen, __ATOMIC_RELAXED, __HIP_MEMORY_SCOPE_AGENT);
        unsigned old = __hip_atomic_fetch_add(bar_cnt, 1u, __ATOMIC_RELAXED, __HIP_MEMORY_SCOPE_AGENT);
        if (old == (unsigned)(NBLK - 1)) {
            __hip_atomic_store(bar_cnt, 0u, __ATOMIC_RELAXED, __HIP_MEMORY_SCOPE_AGENT);
            __hip_atomic_store(bar_gen, g + 1u, __ATOMIC_RELEASE, __HIP_MEMORY_SCOPE_AGENT);
        } else {
            while (__hip_atomic_load(bar_gen, __ATOMIC_ACQUIRE, __HIP_MEMORY_SCOPE_AGENT) == g) {
                __builtin_amdgcn_s_sleep(1);
            }
        }
        __threadfence();  // acquire: invalidate CU L1 + XCD L2 before block reads
    }
    __syncthreads();
}

// -------- row_ptr from sorted pre_idx: row_ptr[i] = lower_bound(pre, i) ------
__global__ void build_rowptr(const int* __restrict__ pre, int nE, int* __restrict__ row_ptr) {
    int i = blockIdx.x * blockDim.x + threadIdx.x;
    if (i > NN) return;
    int lo = 0, hi = nE;
    while (lo < hi) {
        int mid = (lo + hi) >> 1;
        if (pre[mid] < i) lo = mid + 1; else hi = mid;
    }
    row_ptr[i] = lo;
}

// -------- runs[b*NN + p] = first edge of pre p with post >= b*NPB ------------
// (posts ascending within each pre, so block-b's sub-list of pre p is
//  [runs[b][p], runs[b+1][p]) with runs[64][p] = end of p's list)
__global__ void build_runs(const int* __restrict__ post, const int* __restrict__ row_ptr,
                           int* __restrict__ runs) {
    int wid  = (blockIdx.x * blockDim.x + threadIdx.x) >> 6;
    int lane = threadIdx.x & 63;
    int nw   = (gridDim.x * blockDim.x) >> 6;
    for (int p = wid; p < NN; p += nw) {
        int e0 = row_ptr[p], e1 = row_ptr[p + 1];
        int target = lane * NPB;
        int lo = e0, hi = e1;
        while (lo < hi) {
            int mid = (lo + hi) >> 1;
            if (post[mid] < target) lo = mid + 1; else hi = mid;
        }
        runs[lane * NN + p] = lo;
        if (lane == 0) runs[64 * NN + p] = e1;
    }
}

__global__ void init_ws(unsigned* scount, unsigned* bar) {
    int i = blockIdx.x * blockDim.x + threadIdx.x;
    if (i < TSTEPS) scount[i] = 0u;
    if (i < 2) bar[i] = 0u;
}

// ------------------------------- simulation ----------------------------------
__global__ __launch_bounds__(TPB) void sim(
    const float* __restrict__ bg, const float* __restrict__ tau_m,
    const int* __restrict__ post_idx, const int* __restrict__ runs,
    int* __restrict__ slist, unsigned* __restrict__ scount,
    unsigned* __restrict__ bar, float* __restrict__ out)
{
#pragma clang fp contract(off)
    __shared__ unsigned cnt[NPB];

    const int b   = blockIdx.x;
    const int lt  = threadIdx.x;
    const int g   = b * NPB + lt;          // owned neuron (if lt < NPB)
    const bool own = (lt < NPB);

    const float JE = (float)(2.0 * (16.0 / 640.0));        // float32(0.05)
    const float JI = (float)(2.0 * (16.0 / 640.0) * 5.0);  // float32(0.25)
    const float DS = (float)0.98019867330675525;           // exp(-0.1/5)
    const float DA = (float)0.99950012497917929;           // exp(-0.1/200)

    float dv = 0.f, v = 0.f, s = 0.f, a = 0.f, spike = 0.f, sum_v = 0.f;
    int ref = 0, sum_spk = 0;
    if (own) {
        dv = expf(-(0.1f / tau_m[g]));
        cnt[lt] = 0u;
    }
    __syncthreads();

    for (int t = 0; t < TSTEPS; ++t) {
        const int p = t & 1;

        // ------------- Phase A: neuron update + global spike append ----------
        if (own) {
            unsigned c = cnt[lt];
            cnt[lt] = 0u;
            float rec = (float)(c & 0xFFFFu) * JE - (float)(c >> 16) * JI;
            float bgt = bg[t * NN + g];
            s = s * DS + rec + bgt;
            a = a * DA + spike;
            bool active = (ref <= 0);
            v = active ? (v * dv + s) : 0.f;
            float thr = 20.0f + 1.6f * a;
            bool ns = (v >= thr) && active;
            if (ns) v = 0.f;
            ref = ns ? TREF : (ref > 0 ? ref - 1 : 0);
            spike = ns ? 1.f : 0.f;
            sum_spk += ns ? 1 : 0;
            sum_v += v;
            if (ns) {
                unsigned pos = atomicAdd(&scount[t], 1u);
                slist[p * NN + (int)pos] = g;
            }
        }

        grid_sync(&bar[0], &bar[1]);

        // ------------- Phase B: spike-driven scatter into LDS counts ---------
        unsigned k = __hip_atomic_load(&scount[t], __ATOMIC_RELAXED, __HIP_MEMORY_SCOPE_AGENT);
        const int base = b * NPB;
        for (unsigned idx = (unsigned)lt; idx < k; idx += TPB) {
            int sp = slist[p * NN + (int)idx];
            int e0 = runs[b * NN + sp];
            int e1 = runs[(b + 1) * NN + sp];
            unsigned incr = (sp < NEXC) ? 1u : 0x10000u;   // exc lo16 / inh hi16
            for (int e = e0; e < e1; ++e) {
                atomicAdd(&cnt[post_idx[e] - base], incr);
            }
        }
        __syncthreads();   // cnt complete before next step's Phase A reads it
    }

    if (own) {
        out[g]      = (float)sum_spk / 200.0f;
        out[NN + g] = sum_v / 200.0f;
    }
}

// ------------------------------- launcher ------------------------------------
extern "C" void kernel_launch(void* const* d_in, const int* in_sizes, int n_in,
                              void* d_out, int out_size, void* d_ws, size_t ws_size,
                              hipStream_t stream) {
    const float* bg       = (const float*)d_in[1];
    const float* tau_m    = (const float*)d_in[2];
    const int*   pre_idx  = (const int*)d_in[3];
    const int*   post_idx = (const int*)d_in[4];
    const int    nE       = in_sizes[0];
    float* out = (float*)d_out;

    char* ws = (char*)d_ws;
    size_t off = 0;
    int* runs = (int*)(ws + off);            off += (size_t)65 * NN * 4;   // 2,080,000
    int* row_ptr = (int*)(ws + off);         off += (size_t)(NN + 1) * 4;  // 32,004
    off = (off + 15) & ~(size_t)15;
    int* slist = (int*)(ws + off);           off += (size_t)2 * NN * 4;    // 64,000
    unsigned* scount = (unsigned*)(ws + off); off += (size_t)TSTEPS * 4;   // 800
    unsigned* barp = (unsigned*)(ws + off);   off += 2 * 4;

    hipLaunchKernelGGL(build_rowptr, dim3(32), dim3(256), 0, stream, pre_idx, nE, row_ptr);
    hipLaunchKernelGGL(build_runs, dim3(256), dim3(256), 0, stream, post_idx, row_ptr, runs);
    hipLaunchKernelGGL(init_ws, dim3(1), dim3(256), 0, stream, scount, barp);
    hipLaunchKernelGGL(sim, dim3(NBLK), dim3(TPB), 0, stream,
                       bg, tau_m, post_idx, runs, slist, scount, barp, out);
}

// Round 3
// 2034.905 us; speedup vs baseline: 2.5047x; 1.5138x over previous
//
#include <hip/hip_runtime.h>

#define NN      8000
#define NEXC    6400
#define TSTEPS  200
#define TREF    20
#define NBLK    64
#define TPB     1024
#define NPB     125            // neurons per block: 64 * 125 = 8000
#define SLAB    128            // spike slab stride per block (>= NPB)

// Relaxed system-scope atomics: execute at the coherent point (bypass the
// non-coherent per-XCD L2) WITHOUT emitting buffer_inv/buffer_wbl2 — the
// per-step L2 nuking is what killed round 2.
#define LOAD_SYS(p)    __hip_atomic_load((p), __ATOMIC_RELAXED, __HIP_MEMORY_SCOPE_SYSTEM)
#define STORE_SYS(p,v) __hip_atomic_store((p), (v), __ATOMIC_RELAXED, __HIP_MEMORY_SCOPE_SYSTEM)

// -------- row_ptr from sorted pre_idx: row_ptr[i] = lower_bound(pre, i) ------
__global__ void build_rowptr(const int* __restrict__ pre, int nE, int* __restrict__ row_ptr) {
    int i = blockIdx.x * blockDim.x + threadIdx.x;
    if (i > NN) return;
    int lo = 0, hi = nE;
    while (lo < hi) {
        int mid = (lo + hi) >> 1;
        if (pre[mid] < i) lo = mid + 1; else hi = mid;
    }
    row_ptr[i] = lo;
}

// -------- runs[b*NN + p] = first edge of pre p with post >= b*NPB ------------
__global__ void build_runs(const int* __restrict__ post, const int* __restrict__ row_ptr,
                           int* __restrict__ runs) {
    int wid  = (blockIdx.x * blockDim.x + threadIdx.x) >> 6;
    int lane = threadIdx.x & 63;
    int nw   = (gridDim.x * blockDim.x) >> 6;
    for (int p = wid; p < NN; p += nw) {
        int e0 = row_ptr[p], e1 = row_ptr[p + 1];
        int target = lane * NPB;
        int lo = e0, hi = e1;
        while (lo < hi) {
            int mid = (lo + hi) >> 1;
            if (post[mid] < target) lo = mid + 1; else hi = mid;
        }
        runs[lane * NN + p] = lo;
        if (lane == 0) runs[64 * NN + p] = e1;
    }
}

__global__ void init_ws(unsigned* scnt, unsigned* flag) {
    int i = blockIdx.x * blockDim.x + threadIdx.x;
    if (i < 2 * NBLK) scnt[i] = 0u;
    if (i < NBLK) flag[i] = 0u;
}

// ------------------------------- simulation ----------------------------------
__global__ __launch_bounds__(TPB) void sim(
    const float* __restrict__ bg, const float* __restrict__ tau_m,
    const int* __restrict__ post_idx, const int* __restrict__ runs,
    int* __restrict__ slist, unsigned* __restrict__ scnt,
    unsigned* __restrict__ flag, float* __restrict__ out)
{
#pragma clang fp contract(off)
    __shared__ unsigned cnt[NPB];      // packed exc/inh input counts
    __shared__ int      sl_sh[NPB];    // this block's spikers this step
    __shared__ int      nspk_sh[2];    // per-parity spike counter
    __shared__ int      pref_sh[NBLK + 1];

    const int b  = blockIdx.x;
    const int lt = threadIdx.x;
    const int g  = b * NPB + lt;
    const bool own = (lt < NPB);

    const float JE = (float)(2.0 * (16.0 / 640.0));        // float32(0.05)
    const float JI = (float)(2.0 * (16.0 / 640.0) * 5.0);  // float32(0.25)
    const float DS = (float)0.98019867330675525;           // exp(-0.1/5)
    const float DA = (float)0.99950012497917929;           // exp(-0.1/200)

    float dv = 0.f, v = 0.f, s = 0.f, a = 0.f, spike = 0.f, sum_v = 0.f;
    int ref = 0, sum_spk = 0;
    if (own) {
        dv = expf(-(0.1f / tau_m[g]));
        cnt[lt] = 0u;
    }
    if (lt < 2) nspk_sh[lt] = 0;
    __syncthreads();

    for (int t = 0; t < TSTEPS; ++t) {
        const int p = t & 1;

        // ------------- Phase A: neuron update, spikers -> LDS list -----------
        if (own) {
            unsigned c = cnt[lt];
            cnt[lt] = 0u;
            float rec = (float)(c & 0xFFFFu) * JE - (float)(c >> 16) * JI;
            float bgt = bg[t * NN + g];
            s = s * DS + rec + bgt;
            a = a * DA + spike;
            bool active = (ref <= 0);
            v = active ? (v * dv + s) : 0.f;
            float thr = 20.0f + 1.6f * a;
            bool ns = (v >= thr) && active;
            if (ns) v = 0.f;
            ref = ns ? TREF : (ref > 0 ? ref - 1 : 0);
            spike = ns ? 1.f : 0.f;
            sum_spk += ns ? 1 : 0;
            sum_v += v;
            if (ns) {
                int pos = atomicAdd(&nspk_sh[p], 1);
                sl_sh[pos] = g;
            }
        }
        __syncthreads();                                   // sync1

        const int k_local = nspk_sh[p];
        if (lt == 0) nspk_sh[p ^ 1] = 0;                   // reset for step t+1
        if (lt < k_local)
            STORE_SYS(&slist[p * (NBLK * SLAB) + b * SLAB + lt], sl_sh[lt]);
        if (lt == 0)
            STORE_SYS(&scnt[p * NBLK + b], (unsigned)k_local);
        asm volatile("s_waitcnt vmcnt(0)" ::: "memory");   // drain write-through stores
        __syncthreads();                                   // sync2: all drained

        // ------------- fence-free flag barrier + count gather ----------------
        if (lt == 0)
            STORE_SYS(&flag[b], (unsigned)(t + 1));
        if (lt < NBLK) {
            const unsigned need = (unsigned)(t + 1);
            unsigned fv;
            do {
                fv = LOAD_SYS(&flag[lt]);
            } while (__all((int)(fv >= need)) == 0);
            int x = (int)LOAD_SYS(&scnt[p * NBLK + lt]);
            // inclusive 64-lane scan
            for (int off = 1; off < NBLK; off <<= 1) {
                int u = __shfl_up(x, off, 64);
                if (lt >= off) x += u;
            }
            pref_sh[lt + 1] = x;
            if (lt == 0) pref_sh[0] = 0;
        }
        __syncthreads();                                   // sync3

        // ------------- Phase B: spike-driven scatter into LDS counts ---------
        const int ktot = pref_sh[NBLK];
        const int base = b * NPB;
        for (int idx = lt; idx < ktot; idx += TPB) {
            int lo = 0, hi = NBLK;                         // find owning slab
            while (lo + 1 < hi) {
                int mid = (lo + hi) >> 1;
                if (pref_sh[mid] <= idx) lo = mid; else hi = mid;
            }
            int sp = LOAD_SYS(&slist[p * (NBLK * SLAB) + lo * SLAB + (idx - pref_sh[lo])]);
            int e0 = runs[b * NN + sp];
            int e1 = runs[(b + 1) * NN + sp];
            unsigned incr = (sp < NEXC) ? 1u : 0x10000u;   // exc lo16 / inh hi16
            for (int e = e0; e < e1; ++e) {
                atomicAdd(&cnt[post_idx[e] - base], incr);
            }
        }
        __syncthreads();                                   // sync4: cnt ready
    }

    if (own) {
        out[g]      = (float)sum_spk / 200.0f;
        out[NN + g] = sum_v / 200.0f;
    }
}

// ------------------------------- launcher ------------------------------------
extern "C" void kernel_launch(void* const* d_in, const int* in_sizes, int n_in,
                              void* d_out, int out_size, void* d_ws, size_t ws_size,
                              hipStream_t stream) {
    const float* bg       = (const float*)d_in[1];
    const float* tau_m    = (const float*)d_in[2];
    const int*   pre_idx  = (const int*)d_in[3];
    const int*   post_idx = (const int*)d_in[4];
    const int    nE       = in_sizes[0];
    float* out = (float*)d_out;

    char* ws = (char*)d_ws;
    size_t off = 0;
    int* runs    = (int*)(ws + off);          off += (size_t)65 * NN * 4;        // 2,080,000
    int* row_ptr = (int*)(ws + off);          off += (size_t)(NN + 1) * 4;       // 32,004
    off = (off + 15) & ~(size_t)15;
    int* slist   = (int*)(ws + off);          off += (size_t)2 * NBLK * SLAB * 4; // 65,536
    unsigned* scnt = (unsigned*)(ws + off);   off += (size_t)2 * NBLK * 4;       // 512
    unsigned* flag = (unsigned*)(ws + off);   off += (size_t)NBLK * 4;           // 256

    hipLaunchKernelGGL(build_rowptr, dim3(32), dim3(256), 0, stream, pre_idx, nE, row_ptr);
    hipLaunchKernelGGL(build_runs, dim3(256), dim3(256), 0, stream, post_idx, row_ptr, runs);
    hipLaunchKernelGGL(init_ws, dim3(1), dim3(256), 0, stream, scnt, flag);
    hipLaunchKernelGGL(sim, dim3(NBLK), dim3(TPB), 0, stream,
                       bg, tau_m, post_idx, runs, slist, scnt, flag, out);
}

// Round 5
// 1599.554 us; speedup vs baseline: 3.1865x; 1.2722x over previous
//
#include <hip/hip_runtime.h>

#define NN      8000
#define NEXC    6400
#define TSTEPS  200
#define TREF    20
#define NBLK    64
#define TPB     1024
#define NPB     125            // neurons per block: 64 * 125 = 8000

typedef unsigned int u32x4 __attribute__((ext_vector_type(4)));

// 16B coherent-point (UC) access: sc0 sc1 bypass L1 + non-coherent XCD L2.
// Single dwordx4 transaction carries data+tag together -> one round trip.
// ext_vector_type (not HIP's struct uint4) so asm 'v' can bind a VGPR quad.
__device__ __forceinline__ void store_uc16(unsigned* p, u32x4 v) {
    asm volatile("global_store_dwordx4 %0, %1, off sc0 sc1"
                 :: "v"(p), "v"(v) : "memory");
}
__device__ __forceinline__ u32x4 load_uc16(unsigned* p) {
    u32x4 r;
    asm volatile("global_load_dwordx4 %0, %1, off sc0 sc1\n\t"
                 "s_waitcnt vmcnt(0)"
                 : "=v"(r) : "v"(p) : "memory");
    return r;
}

// -------- row_ptr from sorted pre_idx: row_ptr[i] = lower_bound(pre, i) ------
__global__ void build_rowptr(const int* __restrict__ pre, int nE, int* __restrict__ row_ptr) {
    int i = blockIdx.x * blockDim.x + threadIdx.x;
    if (i > NN) return;
    int lo = 0, hi = nE;
    while (lo < hi) {
        int mid = (lo + hi) >> 1;
        if (pre[mid] < i) lo = mid + 1; else hi = mid;
    }
    row_ptr[i] = lo;
}

// -------- runs[b*NN + p] = first edge of pre p with post >= b*NPB ------------
__global__ void build_runs(const int* __restrict__ post, const int* __restrict__ row_ptr,
                           int* __restrict__ runs) {
    int wid  = (blockIdx.x * blockDim.x + threadIdx.x) >> 6;
    int lane = threadIdx.x & 63;
    int nw   = (gridDim.x * blockDim.x) >> 6;
    for (int p = wid; p < NN; p += nw) {
        int e0 = row_ptr[p], e1 = row_ptr[p + 1];
        int target = lane * NPB;
        int lo = e0, hi = e1;
        while (lo < hi) {
            int mid = (lo + hi) >> 1;
            if (post[mid] < target) lo = mid + 1; else hi = mid;
        }
        runs[lane * NN + p] = lo;
        if (lane == 0) runs[64 * NN + p] = e1;
    }
}

__global__ void init_ws(unsigned* chunks) {
    int i = blockIdx.x * blockDim.x + threadIdx.x;
    if (i < 2 * NBLK * 4) chunks[i] = 0u;
}

// ------------------------------- simulation ----------------------------------
__global__ __launch_bounds__(TPB) void sim(
    const float* __restrict__ bg, const float* __restrict__ tau_m,
    const int* __restrict__ post_idx, const int* __restrict__ runs,
    unsigned* __restrict__ chunks, float* __restrict__ out)
{
#pragma clang fp contract(off)
    __shared__ unsigned cnt[NPB];         // packed exc/inh input counts
    __shared__ unsigned mybits[4];        // this block's 125 spike bits
    __shared__ unsigned allb[NBLK * 4];   // gathered global bitmap (8000 bits)
    __shared__ int      list_sh[NN];      // spiker ids this step (worst case NN)
    __shared__ int      nspk_sh;

    const int b  = blockIdx.x;
    const int lt = threadIdx.x;
    const int g  = b * NPB + lt;
    const bool own = (lt < NPB);

    const float JE = (float)(2.0 * (16.0 / 640.0));        // float32(0.05)
    const float JI = (float)(2.0 * (16.0 / 640.0) * 5.0);  // float32(0.25)
    const float DS = (float)0.98019867330675525;           // exp(-0.1/5)
    const float DA = (float)0.99950012497917929;           // exp(-0.1/200)

    float dv = 0.f, v = 0.f, s = 0.f, a = 0.f, spike = 0.f, sum_v = 0.f;
    int ref = 0, sum_spk = 0;
    float bg_cur = 0.f;
    if (own) {
        dv = expf(-(0.1f / tau_m[g]));
        cnt[lt] = 0u;
        bg_cur = bg[g];                    // prefetch t=0 row
    }
    if (lt < 4)  mybits[lt] = 0u;
    if (lt == 0) nspk_sh = 0;
    __syncthreads();

    for (int t = 0; t < TSTEPS; ++t) {
        // ------------- Phase A: neuron update, spike -> bitmap ---------------
        if (own) {
            unsigned c = cnt[lt];
            cnt[lt] = 0u;
            float rec = (float)(c & 0xFFFFu) * JE - (float)(c >> 16) * JI;
            s = s * DS + rec + bg_cur;
            a = a * DA + spike;
            bool active = (ref <= 0);
            v = active ? (v * dv + s) : 0.f;
            float thr = 20.0f + 1.6f * a;
            bool ns = (v >= thr) && active;
            if (ns) v = 0.f;
            ref = ns ? TREF : (ref > 0 ? ref - 1 : 0);
            spike = ns ? 1.f : 0.f;
            sum_spk += ns ? 1 : 0;
            sum_v += v;
            if (ns) atomicOr(&mybits[lt >> 5], 1u << (lt & 31));
        }
        __syncthreads();                                   // bits complete

        // ------------- publish: ONE 16B UC store (bits + 3-bit tag) ----------
        if (lt == 0) {
            u32x4 ch;
            ch[0] = mybits[0]; ch[1] = mybits[1]; ch[2] = mybits[2];
            ch[3] = mybits[3] | (((unsigned)((t + 1) & 7)) << 29);
            store_uc16(&chunks[((t & 1) * NBLK + b) * 4], ch);
        }
        if (own && (t + 1) < TSTEPS)
            bg_cur = bg[(t + 1) * NN + g];                 // hide under poll
        __syncthreads();                                   // t0 done reading mybits
        if (lt < 4)  mybits[lt] = 0u;
        if (lt == 0) nspk_sh = 0;

        // ------------- poll: 64 lanes each watch one block's chunk -----------
        if (lt < NBLK) {
            const unsigned want = ((unsigned)((t + 1) & 7)) << 29;
            u32x4 c;
            for (;;) {
                c = load_uc16(&chunks[((t & 1) * NBLK + lt) * 4]);
                if ((c[3] & 0xE0000000u) == want) break;
                __builtin_amdgcn_s_sleep(1);
            }
            allb[lt * 4 + 0] = c[0];
            allb[lt * 4 + 1] = c[1];
            allb[lt * 4 + 2] = c[2];
            allb[lt * 4 + 3] = c[3] & 0x1FFFFFFFu;
        }
        __syncthreads();                                   // allb ready

        // ------------- bitmap -> spiker list (LDS) ---------------------------
        if (lt < NBLK * 4) {
            unsigned w = allb[lt];
            int n0 = (lt >> 2) * NPB + (lt & 3) * 32;
            while (w) {
                int j = __ffs(w) - 1;
                w &= w - 1;
                int pos = atomicAdd(&nspk_sh, 1);
                list_sh[pos] = n0 + j;
            }
        }
        __syncthreads();

        // ------------- Phase B: spike-driven scatter into LDS counts ---------
        const int ktot = nspk_sh;
        const int base = b * NPB;
        for (int idx = lt; idx < ktot; idx += TPB) {
            int sp = list_sh[idx];
            int e0 = runs[b * NN + sp];
            int e1 = runs[(b + 1) * NN + sp];
            unsigned incr = (sp < NEXC) ? 1u : 0x10000u;   // exc lo16 / inh hi16
            for (int e = e0; e < e1; ++e) {
                atomicAdd(&cnt[post_idx[e] - base], incr);
            }
        }
        __syncthreads();                                   // cnt ready for t+1
    }

    if (own) {
        out[g]      = (float)sum_spk / 200.0f;
        out[NN + g] = sum_v / 200.0f;
    }
}

// ------------------------------- launcher ------------------------------------
extern "C" void kernel_launch(void* const* d_in, const int* in_sizes, int n_in,
                              void* d_out, int out_size, void* d_ws, size_t ws_size,
                              hipStream_t stream) {
    const float* bg       = (const float*)d_in[1];
    const float* tau_m    = (const float*)d_in[2];
    const int*   pre_idx  = (const int*)d_in[3];
    const int*   post_idx = (const int*)d_in[4];
    const int    nE       = in_sizes[0];
    float* out = (float*)d_out;

    char* ws = (char*)d_ws;
    size_t off = 0;
    int* runs    = (int*)(ws + off);       off += (size_t)65 * NN * 4;     // 2,080,000
    int* row_ptr = (int*)(ws + off);       off += (size_t)(NN + 1) * 4;    // 32,004
    off = (off + 15) & ~(size_t)15;
    unsigned* chunks = (unsigned*)(ws + off); off += (size_t)2 * NBLK * 16; // 2,048

    hipLaunchKernelGGL(build_rowptr, dim3(32), dim3(256), 0, stream, pre_idx, nE, row_ptr);
    hipLaunchKernelGGL(build_runs, dim3(256), dim3(256), 0, stream, post_idx, row_ptr, runs);
    hipLaunchKernelGGL(init_ws, dim3(1), dim3(512), 0, stream, chunks);
    hipLaunchKernelGGL(sim, dim3(NBLK), dim3(TPB), 0, stream,
                       bg, tau_m, post_idx, runs, chunks, out);
}

// Round 6
// 1123.515 us; speedup vs baseline: 4.5366x; 1.4237x over previous
//
#include <hip/hip_runtime.h>

#define NN      8000
#define NEXC    6400
#define TSTEPS  200
#define TREF    20
#define NBLK    64
#define TPB     1024
#define NPB     125            // neurons per block: 64 * 125 = 8000
#define EPB     112000         // per-block edge capacity (mean 100K, sigma ~300)

typedef unsigned int u32x4 __attribute__((ext_vector_type(4)));

// 16B coherent-point (UC) access: sc0 sc1 bypass L1 + non-coherent XCD L2.
// Single dwordx4 transaction carries data+tag together -> one round trip.
__device__ __forceinline__ void store_uc16(unsigned* p, u32x4 v) {
    asm volatile("global_store_dwordx4 %0, %1, off sc0 sc1"
                 :: "v"(p), "v"(v) : "memory");
}
__device__ __forceinline__ u32x4 load_uc16(unsigned* p) {
    u32x4 r;
    asm volatile("global_load_dwordx4 %0, %1, off sc0 sc1\n\t"
                 "s_waitcnt vmcnt(0)"
                 : "=v"(r) : "v"(p) : "memory");
    return r;
}

// -------- row_ptr from sorted pre_idx: row_ptr[i] = lower_bound(pre, i) ------
__global__ void build_rowptr(const int* __restrict__ pre, int nE, int* __restrict__ row_ptr) {
    int i = blockIdx.x * blockDim.x + threadIdx.x;
    if (i > NN) return;
    int lo = 0, hi = nE;
    while (lo < hi) {
        int mid = (lo + hi) >> 1;
        if (pre[mid] < i) lo = mid + 1; else hi = mid;
    }
    row_ptr[i] = lo;
}

// -------- runs[b*NN + p] = first edge of pre p with post >= b*NPB ------------
__global__ void build_runs(const int* __restrict__ post, const int* __restrict__ row_ptr,
                           int* __restrict__ runs) {
    int wid  = (blockIdx.x * blockDim.x + threadIdx.x) >> 6;
    int lane = threadIdx.x & 63;
    int nw   = (gridDim.x * blockDim.x) >> 6;
    for (int p = wid; p < NN; p += nw) {
        int e0 = row_ptr[p], e1 = row_ptr[p + 1];
        int target = lane * NPB;
        int lo = e0, hi = e1;
        while (lo < hi) {
            int mid = (lo + hi) >> 1;
            if (post[mid] < target) lo = mid + 1; else hi = mid;
        }
        runs[lane * NN + p] = lo;
        if (lane == 0) runs[64 * NN + p] = e1;
    }
}

// -------- per-block compacted CSC: brp[b][p] offsets + bedge ushort posts ----
// Block b's in-edges live contiguously in bedge[b*EPB ...], grouped by pre,
// local post id in [0,125). Region ~200KB -> stays resident in the XCD L2.
__global__ __launch_bounds__(1024) void build_brp(
    const int* __restrict__ post, const int* __restrict__ runs,
    int* __restrict__ brp, unsigned short* __restrict__ bedge)
{
    __shared__ int wsum[16];
    const int b = blockIdx.x, lt = threadIdx.x;
    const int p0 = lt * 8;                       // 8 pres per thread
    int cnts[8]; int loc = 0;
    for (int j = 0; j < 8; ++j) {
        int p = p0 + j;
        int c = (p < NN) ? (runs[(b + 1) * NN + p] - runs[b * NN + p]) : 0;
        cnts[j] = c; loc += c;
    }
    int x = loc;                                  // wave-inclusive scan
    for (int off = 1; off < 64; off <<= 1) {
        int u = __shfl_up(x, off, 64);
        if ((lt & 63) >= off) x += u;
    }
    if ((lt & 63) == 63) wsum[lt >> 6] = x;
    __syncthreads();
    if (lt < 16) {                                // scan the 16 wave sums
        int y = wsum[lt];
        for (int off = 1; off < 16; off <<= 1) {
            int u = __shfl_up(y, off, 16);
            if (lt >= off) y += u;
        }
        wsum[lt] = y;                             // inclusive
    }
    __syncthreads();
    int base = x - loc + ((lt >> 6) ? wsum[(lt >> 6) - 1] : 0);  // excl prefix
    for (int j = 0; j < 8; ++j) {
        int p = p0 + j;
        if (p < NN) {
            brp[b * (NN + 1) + p] = base;
            int e0 = runs[b * NN + p];
            for (int k = 0; k < cnts[j]; ++k)
                bedge[(size_t)b * EPB + base + k] =
                    (unsigned short)(post[e0 + k] - b * NPB);
            base += cnts[j];
        }
    }
    if (lt == 1023) brp[b * (NN + 1) + NN] = base;
}

__global__ void init_ws(unsigned* chunks) {
    int i = blockIdx.x * blockDim.x + threadIdx.x;
    if (i < 2 * NBLK * 4) chunks[i] = 0u;
}

// ------------------------------- simulation ----------------------------------
__global__ __launch_bounds__(TPB) void sim(
    const float* __restrict__ bg, const float* __restrict__ tau_m,
    const int* __restrict__ brp, const unsigned short* __restrict__ bedge,
    unsigned* __restrict__ chunks, float* __restrict__ out)
{
#pragma clang fp contract(off)
    __shared__ unsigned cnt[NPB];         // packed exc/inh input counts
    __shared__ unsigned mybits[4];        // this block's 125 spike bits
    __shared__ unsigned allb[NBLK * 4];   // gathered global bitmap (8000 bits)
    __shared__ int      list_sh[NN];      // spiker ids this step
    __shared__ int      nspk_sh;

    const int b  = blockIdx.x;
    const int lt = threadIdx.x;
    const int g  = b * NPB + lt;
    const bool own = (lt < NPB);
    const int* __restrict__ brp_b = brp + b * (NN + 1);
    const unsigned short* __restrict__ bedge_b = bedge + (size_t)b * EPB;

    const float JE = (float)(2.0 * (16.0 / 640.0));        // float32(0.05)
    const float JI = (float)(2.0 * (16.0 / 640.0) * 5.0);  // float32(0.25)
    const float DS = (float)0.98019867330675525;           // exp(-0.1/5)
    const float DA = (float)0.99950012497917929;           // exp(-0.1/200)

    float dv = 0.f, v = 0.f, s = 0.f, a = 0.f, spike = 0.f, sum_v = 0.f;
    int ref = 0, sum_spk = 0;
    float bg_cur = 0.f;
    if (own) {
        dv = expf(-(0.1f / tau_m[g]));
        cnt[lt] = 0u;
        bg_cur = bg[g];                    // prefetch t=0 row
    }
    if (lt < 4)  mybits[lt] = 0u;
    if (lt == 0) nspk_sh = 0;
    __syncthreads();

    for (int t = 0; t < TSTEPS; ++t) {
        // ------------- Phase A: neuron update, spike -> bitmap ---------------
        if (own) {
            unsigned c = cnt[lt];
            cnt[lt] = 0u;
            float rec = (float)(c & 0xFFFFu) * JE - (float)(c >> 16) * JI;
            s = s * DS + rec + bg_cur;
            a = a * DA + spike;
            bool active = (ref <= 0);
            v = active ? (v * dv + s) : 0.f;
            float thr = 20.0f + 1.6f * a;
            bool ns = (v >= thr) && active;
            if (ns) v = 0.f;
            ref = ns ? TREF : (ref > 0 ? ref - 1 : 0);
            spike = ns ? 1.f : 0.f;
            sum_spk += ns ? 1 : 0;
            sum_v += v;
            if (ns) atomicOr(&mybits[lt >> 5], 1u << (lt & 31));
        }
        __syncthreads();                                   // bits complete

        // ------------- publish: ONE 16B UC store (bits + 3-bit tag) ----------
        if (lt == 0) {
            u32x4 ch;
            ch[0] = mybits[0]; ch[1] = mybits[1]; ch[2] = mybits[2];
            ch[3] = mybits[3] | (((unsigned)((t + 1) & 7)) << 29);
            store_uc16(&chunks[((t & 1) * NBLK + b) * 4], ch);
        }
        if (own && (t + 1) < TSTEPS)
            bg_cur = bg[(t + 1) * NN + g];                 // hide under poll
        __syncthreads();                                   // done reading mybits
        if (lt < 4)  mybits[lt] = 0u;
        if (lt == 0) nspk_sh = 0;

        // ------------- poll: 64 lanes each watch one block's chunk -----------
        if (lt < NBLK) {
            const unsigned want = ((unsigned)((t + 1) & 7)) << 29;
            u32x4 c;
            for (;;) {
                c = load_uc16(&chunks[((t & 1) * NBLK + lt) * 4]);
                if ((c[3] & 0xE0000000u) == want) break;
                __builtin_amdgcn_s_sleep(1);
            }
            allb[lt * 4 + 0] = c[0];
            allb[lt * 4 + 1] = c[1];
            allb[lt * 4 + 2] = c[2];
            allb[lt * 4 + 3] = c[3] & 0x1FFFFFFFu;
        }
        __syncthreads();                                   // allb ready

        // ------------- bitmap -> spiker list (LDS) ---------------------------
        if (lt < NBLK * 4) {
            unsigned w = allb[lt];
            int n0 = (lt >> 2) * NPB + (lt & 3) * 32;
            while (w) {
                int j = __ffs(w) - 1;
                w &= w - 1;
                int pos = atomicAdd(&nspk_sh, 1);
                list_sh[pos] = n0 + j;
            }
        }
        __syncthreads();

        // ------------- Phase B: scatter via L2-resident block-local CSC ------
        const int ktot = nspk_sh;
        for (int idx = lt; idx < ktot; idx += TPB) {
            int sp = list_sh[idx];
            int o0 = brp_b[sp];
            int o1 = brp_b[sp + 1];
            unsigned incr = (sp < NEXC) ? 1u : 0x10000u;   // exc lo16 / inh hi16
            for (int e = o0; e < o1; ++e) {
                atomicAdd(&cnt[bedge_b[e]], incr);
            }
        }
        __syncthreads();                                   // cnt ready for t+1
    }

    if (own) {
        out[g]      = (float)sum_spk / 200.0f;
        out[NN + g] = sum_v / 200.0f;
    }
}

// ------------------------------- launcher ------------------------------------
extern "C" void kernel_launch(void* const* d_in, const int* in_sizes, int n_in,
                              void* d_out, int out_size, void* d_ws, size_t ws_size,
                              hipStream_t stream) {
    const float* bg       = (const float*)d_in[1];
    const float* tau_m    = (const float*)d_in[2];
    const int*   pre_idx  = (const int*)d_in[3];
    const int*   post_idx = (const int*)d_in[4];
    const int    nE       = in_sizes[0];
    float* out = (float*)d_out;

    char* ws = (char*)d_ws;
    size_t off = 0;
    int* runs    = (int*)(ws + off);          off += (size_t)65 * NN * 4;        // 2,080,000
    int* row_ptr = (int*)(ws + off);          off += (size_t)(NN + 1) * 4;       // 32,004
    off = (off + 63) & ~(size_t)63;
    int* brp     = (int*)(ws + off);          off += (size_t)NBLK * (NN + 1) * 4; // 2,048,256
    off = (off + 63) & ~(size_t)63;
    unsigned short* bedge = (unsigned short*)(ws + off); off += (size_t)NBLK * EPB * 2; // 14,336,000
    off = (off + 63) & ~(size_t)63;
    unsigned* chunks = (unsigned*)(ws + off); off += (size_t)2 * NBLK * 16;      // 2,048

    hipLaunchKernelGGL(build_rowptr, dim3(32), dim3(256), 0, stream, pre_idx, nE, row_ptr);
    hipLaunchKernelGGL(build_runs, dim3(256), dim3(256), 0, stream, post_idx, row_ptr, runs);
    hipLaunchKernelGGL(build_brp, dim3(NBLK), dim3(1024), 0, stream, post_idx, runs, brp, bedge);
    hipLaunchKernelGGL(init_ws, dim3(1), dim3(512), 0, stream, chunks);
    hipLaunchKernelGGL(sim, dim3(NBLK), dim3(TPB), 0, stream,
                       bg, tau_m, brp, bedge, chunks, out);
}

// Round 7
// 864.904 us; speedup vs baseline: 5.8930x; 1.2990x over previous
//
#include <hip/hip_runtime.h>

#define NN      8000
#define NEXC    6400
#define TSTEPS  200
#define TREF    20
#define NBLK    64
#define TPB     1024
#define NPB     125            // neurons per block: 64 * 125 = 8000
#define EPB     112000         // per-block edge capacity

typedef unsigned int u32x4 __attribute__((ext_vector_type(4)));

// 16B coherent-point (UC) access: sc0 sc1 bypass L1 + non-coherent XCD L2.
__device__ __forceinline__ void store_uc16(unsigned* p, u32x4 v) {
    asm volatile("global_store_dwordx4 %0, %1, off sc0 sc1"
                 :: "v"(p), "v"(v) : "memory");
}
__device__ __forceinline__ u32x4 load_uc16(unsigned* p) {
    u32x4 r;
    asm volatile("global_load_dwordx4 %0, %1, off sc0 sc1\n\t"
                 "s_waitcnt vmcnt(0)"
                 : "=v"(r) : "v"(p) : "memory");
    return r;
}

// -------- row_ptr from sorted pre_idx: row_ptr[i] = lower_bound(pre, i) ------
__global__ void build_rowptr(const int* __restrict__ pre, int nE, int* __restrict__ row_ptr) {
    int i = blockIdx.x * blockDim.x + threadIdx.x;
    if (i > NN) return;
    int lo = 0, hi = nE;
    while (lo < hi) {
        int mid = (lo + hi) >> 1;
        if (pre[mid] < i) lo = mid + 1; else hi = mid;
    }
    row_ptr[i] = lo;
}

// -------- runs[b*NN + p] = first edge of pre p with post >= b*NPB ------------
__global__ void build_runs(const int* __restrict__ post, const int* __restrict__ row_ptr,
                           int* __restrict__ runs) {
    int wid  = (blockIdx.x * blockDim.x + threadIdx.x) >> 6;
    int lane = threadIdx.x & 63;
    int nw   = (gridDim.x * blockDim.x) >> 6;
    for (int p = wid; p < NN; p += nw) {
        int e0 = row_ptr[p], e1 = row_ptr[p + 1];
        int target = lane * NPB;
        int lo = e0, hi = e1;
        while (lo < hi) {
            int mid = (lo + hi) >> 1;
            if (post[mid] < target) lo = mid + 1; else hi = mid;
        }
        runs[lane * NN + p] = lo;
        if (lane == 0) runs[64 * NN + p] = e1;
    }
}

// -------- per-block compacted CSC: brp[b][p] offsets + bedge ushort posts ----
__global__ __launch_bounds__(1024) void build_brp(
    const int* __restrict__ post, const int* __restrict__ runs,
    int* __restrict__ brp, unsigned short* __restrict__ bedge)
{
    __shared__ int wsum[16];
    const int b = blockIdx.x, lt = threadIdx.x;
    const int p0 = lt * 8;                       // 8 pres per thread
    int cnts[8]; int loc = 0;
    for (int j = 0; j < 8; ++j) {
        int p = p0 + j;
        int c = (p < NN) ? (runs[(b + 1) * NN + p] - runs[b * NN + p]) : 0;
        cnts[j] = c; loc += c;
    }
    int x = loc;                                  // wave-inclusive scan
    for (int off = 1; off < 64; off <<= 1) {
        int u = __shfl_up(x, off, 64);
        if ((lt & 63) >= off) x += u;
    }
    if ((lt & 63) == 63) wsum[lt >> 6] = x;
    __syncthreads();
    if (lt < 16) {
        int y = wsum[lt];
        for (int off = 1; off < 16; off <<= 1) {
            int u = __shfl_up(y, off, 16);
            if (lt >= off) y += u;
        }
        wsum[lt] = y;
    }
    __syncthreads();
    int base = x - loc + ((lt >> 6) ? wsum[(lt >> 6) - 1] : 0);
    for (int j = 0; j < 8; ++j) {
        int p = p0 + j;
        if (p < NN) {
            brp[b * (NN + 1) + p] = base;
            int e0 = runs[b * NN + p];
            for (int k = 0; k < cnts[j]; ++k)
                bedge[(size_t)b * EPB + base + k] =
                    (unsigned short)(post[e0 + k] - b * NPB);
            base += cnts[j];
        }
    }
    if (lt == 1023) brp[b * (NN + 1) + NN] = base;
}

__global__ void init_ws(unsigned* chunks) {
    int i = blockIdx.x * blockDim.x + threadIdx.x;
    if (i < 2 * NBLK * 4) chunks[i] = 0u;
}

// ------------------------------- simulation ----------------------------------
__global__ __launch_bounds__(TPB) void sim(
    const float* __restrict__ bg, const float* __restrict__ tau_m,
    const int* __restrict__ brp, const unsigned short* __restrict__ bedge,
    unsigned* __restrict__ chunks, float* __restrict__ out)
{
#pragma clang fp contract(off)
    __shared__ unsigned cnt[NPB];         // packed exc/inh input counts
    __shared__ unsigned mybits[4];        // this block's 125 spike bits
    __shared__ float    bg_sh[2][NPB];    // double-buffered bg row
    __shared__ int      list_sh[NN];      // global spiker ids this step
    __shared__ int      nspk_sh;

    const int b    = blockIdx.x;
    const int lt   = threadIdx.x;
    const int wave = lt >> 6;
    const int g    = b * NPB + lt;
    const bool own = (lt < NPB);
    const int* __restrict__ brp_b = brp + b * (NN + 1);
    const unsigned short* __restrict__ bedge_b = bedge + (size_t)b * EPB;

    const float JE = (float)(2.0 * (16.0 / 640.0));        // float32(0.05)
    const float JI = (float)(2.0 * (16.0 / 640.0) * 5.0);  // float32(0.25)
    const float DS = (float)0.98019867330675525;           // exp(-0.1/5)
    const float DA = (float)0.99950012497917929;           // exp(-0.1/200)

    float dv = 0.f, v = 0.f, s = 0.f, a = 0.f, spike = 0.f, sum_v = 0.f;
    int ref = 0, sum_spk = 0;
    if (own) {
        dv = expf(-(0.1f / tau_m[g]));
        cnt[lt] = 0u;
    }
    // waves 14-15 prefill bg row for t=0
    if (lt >= TPB - 128) {
        int j = lt - (TPB - 128);
        if (j < NPB) bg_sh[0][j] = bg[b * NPB + j];
    }
    __syncthreads();

    for (int t = 0; t < TSTEPS; ++t) {
        // ------------- Phase A: neuron update, spikes via ballot -------------
        bool ns = false;
        if (own) {
            unsigned c = cnt[lt];
            cnt[lt] = 0u;
            float rec = (float)(c & 0xFFFFu) * JE - (float)(c >> 16) * JI;
            s = s * DS + rec + bg_sh[t & 1][lt];
            a = a * DA + spike;
            bool active = (ref <= 0);
            v = active ? (v * dv + s) : 0.f;
            float thr = 20.0f + 1.6f * a;
            ns = (v >= thr) && active;
            if (ns) v = 0.f;
            ref = ns ? TREF : (ref > 0 ? ref - 1 : 0);
            spike = ns ? 1.f : 0.f;
            sum_spk += ns ? 1 : 0;
            sum_v += v;
        }
        if (wave < 2) {
            unsigned long long bal = __ballot(ns);
            if ((lt & 63) == 0) {
                mybits[wave * 2 + 0] = (unsigned)(bal & 0xFFFFFFFFu);
                mybits[wave * 2 + 1] = (unsigned)(bal >> 32);
            }
        }
        __syncthreads();                           // sync1: mybits, cnt reset

        // ------------- publish + poll/expand (wave 0) ------------------------
        if (lt == 0) {
            u32x4 ch;
            ch[0] = mybits[0]; ch[1] = mybits[1]; ch[2] = mybits[2];
            ch[3] = mybits[3] | (((unsigned)((t + 1) & 7)) << 29);
            store_uc16(&chunks[((t & 1) * NBLK + b) * 4], ch);
        }
        float bgv = 0.f; int bgj = -1;
        if (lt >= TPB - 128 && (t + 1) < TSTEPS) {  // waves 14-15: prefetch bg
            int j = lt - (TPB - 128);
            if (j < NPB) { bgj = j; bgv = bg[(t + 1) * NN + b * NPB + j]; }
        }
        if (lt < NBLK) {
            const unsigned want = ((unsigned)((t + 1) & 7)) << 29;
            u32x4 c;
            for (;;) {
                c = load_uc16(&chunks[((t & 1) * NBLK + lt) * 4]);
                if ((c[3] & 0xE0000000u) == want) break;
            }
            c[3] &= 0x1FFFFFFFu;
            int tot = __popc(c[0]) + __popc(c[1]) + __popc(c[2]) + __popc(c[3]);
            int x = tot;                           // inclusive wave scan
            for (int off = 1; off < 64; off <<= 1) {
                int u = __shfl_up(x, off, 64);
                if (lt >= off) x += u;
            }
            int pos = x - tot;
            int base = lt * NPB;
            #pragma unroll
            for (int w = 0; w < 4; ++w) {
                unsigned wd = c[w];
                while (wd) {
                    int j = __ffs(wd) - 1;
                    wd &= wd - 1;
                    list_sh[pos++] = base + w * 32 + j;
                }
            }
            if (lt == 63) nspk_sh = x;
        }
        __syncthreads();                           // sync2: list + nspk ready

        // ------------- Phase B: scatter, 2 threads per spike ------------------
        const int ktot = nspk_sh;
        for (int i = lt; i < 2 * ktot; i += TPB) {
            int sp = list_sh[i >> 1];
            int o0 = brp_b[sp];
            int o1 = brp_b[sp + 1];
            int mid = (o0 + o1 + 1) >> 1;
            int s0 = (i & 1) ? mid : o0;
            int s1 = (i & 1) ? o1 : mid;
            unsigned incr = (sp < NEXC) ? 1u : 0x10000u;
            for (int e = s0; e < s1; ++e) {
                atomicAdd(&cnt[bedge_b[e]], incr);
            }
        }
        if (bgj >= 0) bg_sh[(t + 1) & 1][bgj] = bgv;
        __syncthreads();                           // sync3: cnt + bg_sh ready
    }

    if (own) {
        out[g]      = (float)sum_spk / 200.0f;
        out[NN + g] = sum_v / 200.0f;
    }
}

// ------------------------------- launcher ------------------------------------
extern "C" void kernel_launch(void* const* d_in, const int* in_sizes, int n_in,
                              void* d_out, int out_size, void* d_ws, size_t ws_size,
                              hipStream_t stream) {
    const float* bg       = (const float*)d_in[1];
    const float* tau_m    = (const float*)d_in[2];
    const int*   pre_idx  = (const int*)d_in[3];
    const int*   post_idx = (const int*)d_in[4];
    const int    nE       = in_sizes[0];
    float* out = (float*)d_out;

    char* ws = (char*)d_ws;
    size_t off = 0;
    int* runs    = (int*)(ws + off);          off += (size_t)65 * NN * 4;
    int* row_ptr = (int*)(ws + off);          off += (size_t)(NN + 1) * 4;
    off = (off + 63) & ~(size_t)63;
    int* brp     = (int*)(ws + off);          off += (size_t)NBLK * (NN + 1) * 4;
    off = (off + 63) & ~(size_t)63;
    unsigned short* bedge = (unsigned short*)(ws + off); off += (size_t)NBLK * EPB * 2;
    off = (off + 63) & ~(size_t)63;
    unsigned* chunks = (unsigned*)(ws + off); off += (size_t)2 * NBLK * 16;

    hipLaunchKernelGGL(build_rowptr, dim3(32), dim3(256), 0, stream, pre_idx, nE, row_ptr);
    hipLaunchKernelGGL(build_runs, dim3(256), dim3(256), 0, stream, post_idx, row_ptr, runs);
    hipLaunchKernelGGL(build_brp, dim3(NBLK), dim3(1024), 0, stream, post_idx, runs, brp, bedge);
    hipLaunchKernelGGL(init_ws, dim3(1), dim3(512), 0, stream, chunks);
    hipLaunchKernelGGL(sim, dim3(NBLK), dim3(TPB), 0, stream,
                       bg, tau_m, brp, bedge, chunks, out);
}